// Round 12
// baseline (75.313 us; speedup 1.0000x reference)
//
#include <hip/hip_runtime.h>
#include <math.h>

#define BATCH 4
#define NN    12288
#define CIN   3
#define NC    4096
#define NG    12
#define NB    128
#define HSTR  9                    // k_mscan 8-channel scan stride

// ws float-offsets
#define SC_OFF 0                              // per group: scale, amin [NG*2]
#define P_OFF  64                             // partials [768][1024]
#define H2_OFF (P_OFF + 768 * 1024)           // scanned hist [NG*4][NB*8]

// ---------- kernel 1: per-group min/max -> scale, amin ---------------------
__launch_bounds__(256)
__global__ void k_stats(const float* __restrict__ spikes, float* __restrict__ ws) {
    int g = blockIdx.x, b = g / CIN, c = g % CIN;
    const float4* row = (const float4*)(spikes + b * NN);
    int tid = threadIdx.x, lane = tid & 63, w = tid >> 6;
    float mn = 1e30f, mx = -1e30f;
    #pragma unroll
    for (int q = 0; q < 12; ++q) {
        int f = tid + q * 256;                // float4 index < 3072
        float4 v4 = row[f];
        float e[4] = {v4.x, v4.y, v4.z, v4.w};
        int r  = (4 * f) % 3;                 // channel of element j=0
        int j0 = (c - r + 3) % 3;             // first j with channel c
        mn = fminf(mn, e[j0]); mx = fmaxf(mx, e[j0]);
        if (j0 + 3 < 4) { mn = fminf(mn, e[j0 + 3]); mx = fmaxf(mx, e[j0 + 3]); }
    }
    #pragma unroll
    for (int off = 32; off; off >>= 1) {
        mn = fminf(mn, __shfl_down(mn, off));
        mx = fmaxf(mx, __shfl_down(mx, off));
    }
    __shared__ float smn[4], smx[4];
    if (lane == 0) { smn[w] = mn; smx[w] = mx; }
    __syncthreads();
    if (tid == 0) {
        float m0 = fminf(fminf(smn[0], smn[1]), fminf(smn[2], smn[3]));
        float m1 = fmaxf(fmaxf(smx[0], smx[1]), fmaxf(smx[2], smx[3]));
        float scale = 0.25f / fmaxf(m1 - m0, 1e-6f);
        ws[SC_OFF + g * 2]     = scale;
        ws[SC_OFF + g * 2 + 1] = m0 * scale;
    }
}

// ---------- kernel 2: u=(elem,d): 2-channel LDS hist -> dense partial ------
// 768 blocks x 256 thr; block = (group g, 64 elems); thread = (elem, dim)
__launch_bounds__(256)
__global__ void k_hist(const float* __restrict__ spikes,
                       const float* __restrict__ theta,
                       float* __restrict__ ws) {
    __shared__ float lh[4 * NB * 3];          // 1536 floats
    int blk = blockIdx.x, g = blk >> 6, j = blk & 63;
    int b = g / CIN, c = g % CIN;
    int tid = threadIdx.x;
    #pragma unroll
    for (int q = 0; q < 6; ++q) lh[tid + q * 256] = 0.f;
    float scale = ws[SC_OFF + g * 2], amin = ws[SC_OFF + g * 2 + 1];
    __syncthreads();

    int k = j * 64 + (tid >> 2);
    int d = tid & 3;
    int v = b * NN + k * CIN + c;
    float a = spikes[v] * scale;              // quad-broadcast load
    int bb = (int)((a - amin) * (4.0f * NB));
    bb = bb < 0 ? 0 : (bb > NB - 1 ? NB - 1 : bb);
    float sth, cth; __sincosf(theta[v * 4 + d], &sth, &cth);
    float* h = lh + (d * NB + bb) * 3;
    atomicAdd(h + 0, sth);
    atomicAdd(h + 1, cth);
    __syncthreads();

    float* P = ws + P_OFF + (size_t)blk * 1024;
    #pragma unroll
    for (int q = 0; q < 4; ++q) {
        int o = tid + q * 256;                // (d*NB+bb)*2 + ch
        P[o] = lh[(o >> 1) * 3 + (o & 1)];
    }
}

// ---------- kernel 3: per (g,d): merge 64 partials, derive 8 ch, scan ------
__launch_bounds__(256)
__global__ void k_mscan(float* __restrict__ ws) {
    __shared__ float raw[256];
    __shared__ float lh[NB * HSTR];           // 1152
    int gd = blockIdx.x, g = gd >> 2, d = gd & 3;
    int tid = threadIdx.x, lane = tid & 63, w = tid >> 6;

    const float* Pg = ws + P_OFF + (size_t)(g * 64) * 1024 + d * 256;
    float s = 0.f;
    #pragma unroll 8
    for (int p = 0; p < 64; ++p) s += Pg[(size_t)p * 1024 + tid];
    raw[tid] = s;
    __syncthreads();

    float amin = ws[SC_OFF + g * 2 + 1];
    if (tid < NB) {
        float Ss = raw[tid * 2], Sc = raw[tid * 2 + 1];
        float abar = amin + ((float)tid + 0.5f) * (0.25f / (float)NB);
        float sa, ca; __sincosf(abar, &sa, &ca);
        float c0 = fmaf(ca, Ss,  sa * Sc);    // ~ sum sin(th + a)
        float c1 = fmaf(ca, Sc, -sa * Ss);    // ~ sum cos(th + a)
        float c4 = fmaf(ca, Ss, -sa * Sc);    // ~ sum sin(th - a)
        float c5 = fmaf(ca, Sc,  sa * Ss);    // ~ sum cos(th - a)
        float* L = lh + tid * HSTR;
        L[0] = c0;        L[1] = c1;
        L[2] = abar * c0; L[3] = abar * c1;
        L[4] = c4;        L[5] = c5;
        L[6] = abar * c4; L[7] = abar * c5;
    }
    __syncthreads();

    // inclusive scan over 128 buckets; 4 waves x 2 channels, 2 buckets/lane
    #pragma unroll
    for (int p = 0; p < 2; ++p) {
        int ch = w * 2 + p;
        float x0 = lh[(lane * 2 + 0) * HSTR + ch];
        float x1 = lh[(lane * 2 + 1) * HSTR + ch];
        float i0 = x0, i1 = i0 + x1;
        float incl = i1;
        #pragma unroll
        for (int off = 1; off < 64; off <<= 1) {
            float o = __shfl_up(incl, off);
            if (lane >= off) incl += o;
        }
        float ebt = incl - i1;
        lh[(lane * 2 + 0) * HSTR + ch] = ebt + i0;
        lh[(lane * 2 + 1) * HSTR + ch] = ebt + i1;
    }
    __syncthreads();

    float* H2 = ws + H2_OFF + (size_t)gd * (NB * 8);
    #pragma unroll
    for (int q = 0; q < 4; ++q) {
        int o = tid + q * 256;
        H2[o] = lh[(o >> 3) * HSTR + (o & 7)];
    }
}

// ---------- kernel 4: u=(node,d): combine + gamma + quad-shfl normalize ----
__launch_bounds__(256)
__global__ void k_apply(const float* __restrict__ spikes,
                        const float* __restrict__ theta,
                        const float* __restrict__ gamma,
                        const float* __restrict__ ws,
                        float* __restrict__ out) {
    int u = blockIdx.x * 256 + threadIdx.x;   // < BATCH*NN*4
    int v = u >> 2, d = u & 3;
    int b = u / (NN * 4);
    int c = v % 3;                            // NN % 3 == 0
    int g = b * CIN + c;
    float scale = ws[SC_OFF + g * 2], amin = ws[SC_OFF + g * 2 + 1];
    float a = spikes[v] * scale;              // quad-broadcast
    int bb = (int)((a - amin) * (4.0f * NB));
    bb = bb < 0 ? 0 : (bb > NB - 1 ? NB - 1 : bb);
    float sa, ca; __sincosf(a, &sa, &ca);
    float sth, cth; __sincosf(theta[u], &sth, &cth);   // coalesced scalar
    float sf = fmaf(cth, sa,  sth * ca);      // sin(th + a), exact i-side
    float cf = fmaf(-sth, sa, cth * ca);      // cos(th + a)
    float sp = fmaf(-cth, sa, sth * ca);      // sin(th - a)
    float cq = fmaf(sth, sa,  cth * ca);      // cos(th - a)
    const float4* Hq = (const float4*)(ws + H2_OFF + (size_t)(g * 4 + d) * (NB * 8));
    float4 Plo = Hq[bb * 2];
    float4 Phi = Hq[bb * 2 + 1];
    float4 T   = Hq[(NB - 1) * 2 + 1];
    float lowS = fmaf(0.25f - a, Plo.x, Plo.z);
    float lowC = fmaf(0.25f - a, Plo.y, Plo.w);
    float lower = cf * lowS - sf * lowC;
    float S4 = T.x - Phi.x, S5 = T.y - Phi.y;
    float S6 = T.z - Phi.z, S7 = T.w - Phi.w;
    float upS = fmaf(0.25f + a, S4, -S6);
    float upC = fmaf(0.25f + a, S5, -S7);
    float upper = cq * upS - sp * upC;
    float cp = (lower + upper) * (1.0f / (float)NC);
    float t = gamma[u] + cp;                  // coalesced scalar
    float n2 = t * t;
    n2 += __shfl_xor(n2, 1);
    n2 += __shfl_xor(n2, 2);
    float inv = 1.0f / fmaxf(sqrtf(n2), 1e-6f);
    out[u] = t * inv;                         // coalesced scalar
}

extern "C" void kernel_launch(void* const* d_in, const int* in_sizes, int n_in,
                              void* d_out, int out_size, void* d_ws, size_t ws_size,
                              hipStream_t stream) {
    const float* theta  = (const float*)d_in[0];
    const float* gamma  = (const float*)d_in[1];
    const float* spikes = (const float*)d_in[2];
    float* out = (float*)d_out;
    float* ws  = (float*)d_ws;

    hipLaunchKernelGGL(k_stats, dim3(NG),              dim3(256), 0, stream, spikes, ws);
    hipLaunchKernelGGL(k_hist,  dim3(NG * 64),         dim3(256), 0, stream, spikes, theta, ws);
    hipLaunchKernelGGL(k_mscan, dim3(NG * 4),          dim3(256), 0, stream, ws);
    hipLaunchKernelGGL(k_apply, dim3(BATCH*NN*4/256),  dim3(256), 0, stream,
                       spikes, theta, gamma, ws, out);
}

// Round 14
// 72.933 us; speedup vs baseline: 1.0326x; 1.0326x over previous
//
#include <hip/hip_runtime.h>
#include <math.h>

#define BATCH 4
#define NN    12288
#define CIN   3
#define NC    4096
#define NG    12
#define NB    128
#define HSTR  9                    // k_mscan 8-channel scan stride
#define CPB   48                   // chunks per batch = NN/256
#define PSZ   (CIN * 4 * NB * 2)   // dense partial per hist block = 3072 floats

// ws float-offsets
#define SC_OFF 0                              // per group: scale, amin [NG*2]
#define P_OFF  64                             // partials [BATCH*CPB][PSZ]
#define H2_OFF (P_OFF + BATCH * CPB * PSZ)    // scanned hist [NG*4][NB*8]

// ---------- kernel 1: per-group min/max -> scale, amin ---------------------
__launch_bounds__(256)
__global__ void k_stats(const float* __restrict__ spikes, float* __restrict__ ws) {
    int g = blockIdx.x, b = g / CIN, c = g % CIN;
    const float4* row = (const float4*)(spikes + b * NN);
    int tid = threadIdx.x, lane = tid & 63, w = tid >> 6;
    float mn = 1e30f, mx = -1e30f;
    #pragma unroll
    for (int q = 0; q < 12; ++q) {
        int f = tid + q * 256;                // float4 index < 3072
        float4 v4 = row[f];
        float e[4] = {v4.x, v4.y, v4.z, v4.w};
        int r  = (4 * f) % 3;                 // channel of element j=0
        int j0 = (c - r + 3) % 3;             // first j with channel c
        mn = fminf(mn, e[j0]); mx = fmaxf(mx, e[j0]);
        if (j0 + 3 < 4) { mn = fminf(mn, e[j0 + 3]); mx = fmaxf(mx, e[j0 + 3]); }
    }
    #pragma unroll
    for (int off = 32; off; off >>= 1) {
        mn = fminf(mn, __shfl_down(mn, off));
        mx = fmaxf(mx, __shfl_down(mx, off));
    }
    __shared__ float smn[4], smx[4];
    if (lane == 0) { smn[w] = mn; smx[w] = mx; }
    __syncthreads();
    if (tid == 0) {
        float m0 = fminf(fminf(smn[0], smn[1]), fminf(smn[2], smn[3]));
        float m1 = fmaxf(fmaxf(smx[0], smx[1]), fmaxf(smx[2], smx[3]));
        float scale = 0.25f / fmaxf(m1 - m0, 1e-6f);
        ws[SC_OFF + g * 2]     = scale;
        ws[SC_OFF + g * 2 + 1] = m0 * scale;
    }
}

// ---------- kernel 2: consecutive-node blocks, 3-group LDS hist ------------
// BATCH*CPB = 192 blocks x 256 thr; block = (batch b, 256 contiguous nodes).
// All loads coalesced; 8 LDS atomics/node; dense 3 KB partial (no glb atomics).
__launch_bounds__(256)
__global__ void k_hist(const float* __restrict__ spikes,
                       const float* __restrict__ theta,
                       float* __restrict__ ws) {
    __shared__ float lh[CIN * 4 * NB * 3];    // 4608 floats
    int blk = blockIdx.x, b = blk / CPB, chunk = blk % CPB;
    int tid = threadIdx.x;
    #pragma unroll
    for (int q = 0; q < 18; ++q) lh[tid + q * 256] = 0.f;

    int r = chunk * 256 + tid;                // node within batch, < NN
    int v = b * NN + r;
    int c = r % 3;
    float scale = ws[SC_OFF + (b * CIN + c) * 2];
    float amin  = ws[SC_OFF + (b * CIN + c) * 2 + 1];
    float a = spikes[v] * scale;              // coalesced
    int bb = (int)((a - amin) * (4.0f * NB));
    bb = bb < 0 ? 0 : (bb > NB - 1 ? NB - 1 : bb);
    float4 th = ((const float4*)theta)[v];    // coalesced
    float thv[4] = {th.x, th.y, th.z, th.w};
    __syncthreads();

    #pragma unroll
    for (int d = 0; d < 4; ++d) {
        float sth, cth; __sincosf(thv[d], &sth, &cth);
        float* h = lh + ((c * 4 + d) * NB + bb) * 3;
        atomicAdd(h + 0, sth);
        atomicAdd(h + 1, cth);
    }
    __syncthreads();

    float* P = ws + P_OFF + (size_t)blk * PSZ;
    #pragma unroll
    for (int q = 0; q < 12; ++q) {
        int o = tid + q * 256;                // ((c*4+d)*NB+bb)*2 + ch
        P[o] = lh[(o >> 1) * 3 + (o & 1)];
    }
}

// ---------- kernel 3: per (g,d): merge CPB partials, derive 8 ch, scan -----
__launch_bounds__(256)
__global__ void k_mscan(float* __restrict__ ws) {
    __shared__ float raw[256];
    __shared__ float lh[NB * HSTR];           // 1152
    int gd = blockIdx.x, g = gd >> 2, d = gd & 3;
    int b = g / CIN, c = g % CIN;
    int tid = threadIdx.x, lane = tid & 63, w = tid >> 6;

    // partials of batch b, slice (c,d): contiguous 256-float runs
    const float* Pg = ws + P_OFF + (size_t)(b * CPB) * PSZ + (c * 4 + d) * (NB * 2);
    float s = 0.f;
    #pragma unroll 8
    for (int p = 0; p < CPB; ++p) s += Pg[(size_t)p * PSZ + tid];
    raw[tid] = s;
    __syncthreads();

    float amin = ws[SC_OFF + g * 2 + 1];
    if (tid < NB) {
        float Ss = raw[tid * 2], Sc = raw[tid * 2 + 1];
        float abar = amin + ((float)tid + 0.5f) * (0.25f / (float)NB);
        float sa, ca; __sincosf(abar, &sa, &ca);
        float c0 = fmaf(ca, Ss,  sa * Sc);    // ~ sum sin(th + a)
        float c1 = fmaf(ca, Sc, -sa * Ss);    // ~ sum cos(th + a)
        float c4 = fmaf(ca, Ss, -sa * Sc);    // ~ sum sin(th - a)
        float c5 = fmaf(ca, Sc,  sa * Ss);    // ~ sum cos(th - a)
        float* L = lh + tid * HSTR;
        L[0] = c0;        L[1] = c1;
        L[2] = abar * c0; L[3] = abar * c1;
        L[4] = c4;        L[5] = c5;
        L[6] = abar * c4; L[7] = abar * c5;
    }
    __syncthreads();

    // inclusive scan over 128 buckets; 4 waves x 2 channels, 2 buckets/lane
    #pragma unroll
    for (int p = 0; p < 2; ++p) {
        int ch = w * 2 + p;
        float x0 = lh[(lane * 2 + 0) * HSTR + ch];
        float x1 = lh[(lane * 2 + 1) * HSTR + ch];
        float i0 = x0, i1 = i0 + x1;
        float incl = i1;
        #pragma unroll
        for (int off = 1; off < 64; off <<= 1) {
            float o = __shfl_up(incl, off);
            if (lane >= off) incl += o;
        }
        float ebt = incl - i1;
        lh[(lane * 2 + 0) * HSTR + ch] = ebt + i0;
        lh[(lane * 2 + 1) * HSTR + ch] = ebt + i1;
    }
    __syncthreads();

    float* H2 = ws + H2_OFF + (size_t)gd * (NB * 8);
    #pragma unroll
    for (int q = 0; q < 4; ++q) {
        int o = tid + q * 256;
        H2[o] = lh[(o >> 3) * HSTR + (o & 7)];
    }
}

// ---------- kernel 4: contiguous nodes, LDS-staged H2, fused epilogue ------
__launch_bounds__(256)
__global__ void k_apply(const float* __restrict__ spikes,
                        const float* __restrict__ theta,
                        const float* __restrict__ gamma,
                        const float* __restrict__ ws,
                        float* __restrict__ out) {
    __shared__ __align__(16) float lH[CIN * 4 * NB * 8];   // 48 KB
    int v = blockIdx.x * 256 + threadIdx.x;   // node (blocks don't straddle b)
    int b = v / NN;

    const float4* src = (const float4*)(ws + H2_OFF + (size_t)b * (CIN * 4 * NB * 8));
    float4* dst = (float4*)lH;
    #pragma unroll
    for (int q = 0; q < 12; ++q) {
        int i = threadIdx.x + q * 256;        // < 3072
        dst[i] = src[i];
    }
    __syncthreads();

    int r = v - b * NN;
    int c = r % 3;
    int g = b * CIN + c;
    float scale = ws[SC_OFF + g * 2], amin = ws[SC_OFF + g * 2 + 1];
    float a = spikes[v] * scale;
    int bb = (int)((a - amin) * (4.0f * NB));
    bb = bb < 0 ? 0 : (bb > NB - 1 ? NB - 1 : bb);
    float sa, ca; __sincosf(a, &sa, &ca);
    float4 th = ((const float4*)theta)[v];
    float4 gm = ((const float4*)gamma)[v];
    float thv[4] = {th.x, th.y, th.z, th.w};
    float cp[4];
    #pragma unroll
    for (int d = 0; d < 4; ++d) {
        float sth, cth; __sincosf(thv[d], &sth, &cth);
        float sf = fmaf(cth, sa,  sth * ca);  // sin(th + a), exact i-side
        float cf = fmaf(-sth, sa, cth * ca);  // cos(th + a)
        float sp = fmaf(-cth, sa, sth * ca);  // sin(th - a)
        float cq = fmaf(sth, sa,  cth * ca);  // cos(th - a)
        const float4* Hq = (const float4*)(lH + (c * 4 + d) * (NB * 8));
        float4 Plo = Hq[bb * 2];
        float4 Phi = Hq[bb * 2 + 1];
        float4 T   = Hq[(NB - 1) * 2 + 1];
        float lowS = fmaf(0.25f - a, Plo.x, Plo.z);
        float lowC = fmaf(0.25f - a, Plo.y, Plo.w);
        float lower = cf * lowS - sf * lowC;
        float S4 = T.x - Phi.x, S5 = T.y - Phi.y;
        float S6 = T.z - Phi.z, S7 = T.w - Phi.w;
        float upS = fmaf(0.25f + a, S4, -S6);
        float upC = fmaf(0.25f + a, S5, -S7);
        float upper = cq * upS - sp * upC;
        cp[d] = (lower + upper) * (1.0f / (float)NC);
    }
    float tx = gm.x + cp[0], ty = gm.y + cp[1];
    float tz = gm.z + cp[2], tw = gm.w + cp[3];
    float nrm = sqrtf(tx * tx + ty * ty + tz * tz + tw * tw);
    float inv = 1.0f / fmaxf(nrm, 1e-6f);
    ((float4*)out)[v] = make_float4(tx * inv, ty * inv, tz * inv, tw * inv);
}

extern "C" void kernel_launch(void* const* d_in, const int* in_sizes, int n_in,
                              void* d_out, int out_size, void* d_ws, size_t ws_size,
                              hipStream_t stream) {
    const float* theta  = (const float*)d_in[0];
    const float* gamma  = (const float*)d_in[1];
    const float* spikes = (const float*)d_in[2];
    float* out = (float*)d_out;
    float* ws  = (float*)d_ws;

    hipLaunchKernelGGL(k_stats, dim3(NG),             dim3(256), 0, stream, spikes, ws);
    hipLaunchKernelGGL(k_hist,  dim3(BATCH * CPB),    dim3(256), 0, stream, spikes, theta, ws);
    hipLaunchKernelGGL(k_mscan, dim3(NG * 4),         dim3(256), 0, stream, ws);
    hipLaunchKernelGGL(k_apply, dim3(BATCH*NN/256),   dim3(256), 0, stream,
                       spikes, theta, gamma, ws, out);
}